// Round 4
// baseline (79.982 us; speedup 1.0000x reference)
//
#include <hip/hip_runtime.h>
#include <math.h>

// Problem constants (setup_inputs): data1/data2 = (2, 4, 4096, 3) fp32, dim = 0.
constexpr int kB   = 2;
constexpr int kT   = 4;
constexpr int kBT  = kB * kT;       // 8 (b,t) slices
constexpr int kN   = 4096;          // points per slice (both sets)
constexpr int kR   = 4;             // set1 points per thread (register-tiled)
constexpr int kBLK = 256;           // threads per block
constexpr int kSP1 = kR * kBLK;     // 1024 set1 points per block
constexpr int kS1C = kN / kSP1;     // 4 set1 chunks
constexpr int kSP2 = 64;            // data2 points per block (chunk)
constexpr int kS2C = kN / kSP2;     // 64 data2 chunks
constexpr int kNG  = kSP2 / 4;      // 16 groups of 4 data2 points (3 float4 each)

// ws layout: partial mins ws[c2][bt][p], c2 in [0,64), p in [0,4096) -> 8 MB.
// Plain coalesced stores (no atomics, no init). Mean accumulated into d_out
// via one atomicAdd per reduce block; d_out zeroed by hd_partial block 0.

// Kernel 1: one block per (bt, set1-chunk c1, data2-chunk c2). 2048 blocks =
// 8 blocks/CU = 8 waves/SIMD (launch_bounds caps VGPRs at 64 to allow it).
// Inner math: s = q2 - 2*dot = d^2 - q1 via 3 fma (set1 pre-scaled by -2);
// q1 added once in the epilogue. 4.25 VALU instr/pair. data2 points processed
// in PAIRS to halve temp liveness (fits the 64-VGPR budget).
__global__ __launch_bounds__(kBLK, 8) void hd_partial(
    const float* __restrict__ d1, const float* __restrict__ d2,
    float* __restrict__ ws, float* __restrict__ out)
{
    const int blk = blockIdx.x;
    const int c2  = blk % kS2C;
    const int t2  = blk / kS2C;
    const int c1  = t2 % kS1C;
    const int bt  = t2 / kS1C;

    const int tid = threadIdx.x;

    // Zero the 2 output accumulators (poisoned 0xAA by the harness each iter).
    // Stream order guarantees this retires before hd_reduce's atomicAdds.
    if (blk == 0 && tid < kB) out[tid] = 0.0f;

    // Per-thread set1 points (registers), pre-scaled by -2 for the fma form.
    const int p0 = c1 * kSP1 + tid;
    const float* __restrict__ base1 = d1 + (size_t)bt * kN * 3;
    float nx[kR], ny[kR], nz[kR], q1[kR], m[kR];
#pragma unroll
    for (int k = 0; k < kR; ++k) {
        const int p = p0 + k * kBLK;
        const float x = base1[p * 3 + 0];
        const float y = base1[p * 3 + 1];
        const float z = base1[p * 3 + 2];
        nx[k] = -2.0f * x; ny[k] = -2.0f * y; nz[k] = -2.0f * z;
        q1[k] = fmaf(x, x, fmaf(y, y, z * z));
        m[k]  = 3.402823466e38f;
    }

    // data2 chunk: 64 pts * 3 floats = 48 float4, block-uniform, 16B aligned
    // (bt*12288 and c2*192 floats are multiples of 4).
    const float4* __restrict__ g2 =
        (const float4*)(d2 + (size_t)bt * kN * 3 + (size_t)c2 * kSP2 * 3);

#pragma unroll 2
    for (int g = 0; g < kNG; ++g) {
        const float4 A  = g2[3 * g + 0];
        const float4 Bv = g2[3 * g + 1];
        const float4 Cv = g2[3 * g + 2];
        const float px[4] = {A.x, A.w, Bv.z, Cv.y};
        const float py[4] = {A.y, Bv.x, Bv.w, Cv.z};
        const float pz[4] = {A.z, Bv.y, Cv.x, Cv.w};
        // Process the 4 data2 points in 2 pairs -> only 2*kR temps live.
#pragma unroll
        for (int jp = 0; jp < 2; ++jp) {
            const int j0 = 2 * jp, j1 = 2 * jp + 1;
            const float q2a = fmaf(px[j0], px[j0],
                              fmaf(py[j0], py[j0], pz[j0] * pz[j0]));
            const float q2b = fmaf(px[j1], px[j1],
                              fmaf(py[j1], py[j1], pz[j1] * pz[j1]));
            float sa[kR], sb[kR];
#pragma unroll
            for (int k = 0; k < kR; ++k) {
                float ta = fmaf(px[j0], nx[k], q2a);
                ta = fmaf(py[j0], ny[k], ta);
                sa[k] = fmaf(pz[j0], nz[k], ta);
                float tb = fmaf(px[j1], nx[k], q2b);
                tb = fmaf(py[j1], ny[k], tb);
                sb[k] = fmaf(pz[j1], nz[k], tb);
            }
#pragma unroll
            for (int k = 0; k < kR; ++k)   // v_min3 per k per pair
                m[k] = fminf(m[k], fminf(sa[k], sb[k]));
        }
    }

    // Coalesced partial-min store (d^2, clamped >= 0 so sqrt is safe).
    float* __restrict__ wrow = ws + ((size_t)c2 * kBT + bt) * kN;
#pragma unroll
    for (int k = 0; k < kR; ++k)
        wrow[p0 + k * kBLK] = fmaxf(m[k] + q1[k], 0.0f);
}

// Kernel 2: 32 blocks (4 per bt). float4 min over the 64 chunk-partials,
// sqrt, block-sum, one atomicAdd per block into out[b].
__global__ __launch_bounds__(256) void hd_reduce(
    const float4* __restrict__ ws4, float* __restrict__ out)
{
    const int bt   = blockIdx.x >> 2;     // 0..7
    const int quad = blockIdx.x & 3;      // 0..3 -> 1024 points each
    const int tid  = threadIdx.x;

    const int p4 = quad * 256 + tid;      // float4 index within the 1024-f4 row
    float4 m4 = make_float4(3.402823466e38f, 3.402823466e38f,
                            3.402823466e38f, 3.402823466e38f);
#pragma unroll 8
    for (int c2 = 0; c2 < kS2C; ++c2) {
        const float4 v = ws4[((size_t)c2 * kBT + bt) * (kN / 4) + p4];
        m4.x = fminf(m4.x, v.x);
        m4.y = fminf(m4.y, v.y);
        m4.z = fminf(m4.z, v.z);
        m4.w = fminf(m4.w, v.w);
    }
    float sum = sqrtf(m4.x) + sqrtf(m4.y) + sqrtf(m4.z) + sqrtf(m4.w);

    // wave (64-lane) reduce
#pragma unroll
    for (int off = 32; off >= 1; off >>= 1)
        sum += __shfl_down(sum, off, 64);

    __shared__ float ls[4];
    if ((tid & 63) == 0) ls[tid >> 6] = sum;
    __syncthreads();
    if (tid == 0) {
        const float tot = ls[0] + ls[1] + ls[2] + ls[3];
        atomicAdd(&out[bt >> 2], tot * (1.0f / (kT * kN)));
    }
}

extern "C" void kernel_launch(void* const* d_in, const int* in_sizes, int n_in,
                              void* d_out, int out_size, void* d_ws, size_t ws_size,
                              hipStream_t stream) {
    const float* d1 = (const float*)d_in[0];
    const float* d2 = (const float*)d_in[1];
    // d_in[2] is dim == 0 -> identity swapaxes; ignored.
    float* out = (float*)d_out;
    float* ws = (float*)d_ws;

    hd_partial<<<dim3(kBT * kS1C * kS2C), dim3(kBLK), 0, stream>>>(d1, d2, ws, out);
    hd_reduce<<<dim3(kBT * 4), dim3(256), 0, stream>>>((const float4*)ws, out);
}